// Round 6
// baseline (403.193 us; speedup 1.0000x reference)
//
#include <hip/hip_runtime.h>

// STFT: N_FFT=1024, HOP=256, WIN=1024, SIG_LEN=2^24, pad=768 each side.
// n_frames=65539 computed frames, n_rows=65542 output rows, half_n=513.
// Circular shift by 512 (zero-phase) == multiply spectrum by (-1)^k (baked
// into the AB tables this round).
//
// FP64 FFT, FP32 TRANSCENDENTALS: sign(Yi) at deep spectral nulls must
// match the fp64 reference -> FFT + untwiddle in fp64; final sqrt/atan2
// in fp32 after casting (sign-preserving).
//
// ROUND-6: the kernel is dependency-stall-bound (no pipe >45%; R5's
// occupancy boost gave ~4 us). Fix = more independent work per wave:
//  - TWO consecutive frames per wave (64-thr blocks, 16 KB LDS). Frames
//    share input loads (768-sample overlap -> 10 float2 instead of 16),
//    share tw1/tw2/window/AB table loads, and share the 3 lgkmcnt drains.
//  - Epilogue from REGISTERS: k = 64*reg + 8*q + g ordering makes Zk a
//    register; only bins 256..511 (regs 4..7) go to LDS for conjugate
//    partners (XOR-swizzled, conflict-free per 8-lane octet).
//    DS ops/frame 48 -> 28; one LDS round-trip off the critical path.
//  - (-1)^k baked into AB tables (valid: (-1)^{512-k} = (-1)^k, so the
//    conj-pair identity Y'_{512-k} = conj(conj(Zm)A' + Zk B') holds).

#define SIG_LEN   16777216
#define N_FRAMES  65539
#define N_ROWS    65542
#define HALF_N    513
#define FRAMES_FLOATS (N_FRAMES * HALF_N)   // 33621507
#define MAG_SZ        (N_ROWS   * HALF_N)   // 33623046

// d_ws layout (doubles):
//   [0, 1024)        window (hamming/32), fp64
//   [1024, 1920)     tw1: 448 x double2, tw1[l*7+r-1] = e^{-2*pi*i*l*r/512}
//   [1920, 2032)     tw2: 56 x double2,  tw2[q*7+r-1] = e^{-2*pi*i*8*q*r/512}
//   [2048, 4100)     AB: 513 x {A.x,A.y,B.x,B.y} * (-1)^k, w=e^{-i*pi*k/512},
//                    A=0.5(1-i*w), B=0.5(1+i*w)

__global__ void init_tables(double* __restrict__ ws) {
  int i = blockIdx.x * 256 + threadIdx.x;
  const double PI = 3.14159265358979323846;
  if (i < 1024) {
    ws[i] = (0.54 - 0.46 * cos(2.0 * PI * (double)i / 1023.0)) / 32.0;
  }
  if (i < 448) {
    int l = i / 7, r = i % 7 + 1;
    double a = -2.0 * PI * (double)(l * r) / 512.0;
    ws[1024 + 2 * i]     = cos(a);
    ws[1024 + 2 * i + 1] = sin(a);
  }
  if (i < 56) {
    int q = i / 7, r = i % 7 + 1;
    double a = -2.0 * PI * (double)(8 * q * r) / 512.0;
    ws[1920 + 2 * i]     = cos(a);
    ws[1920 + 2 * i + 1] = sin(a);
  }
  if (i < 513) {
    double th = PI * (double)i / 512.0;
    double c = cos(th), s = sin(th);
    double sg = (i & 1) ? -1.0 : 1.0;       // (-1)^k baked in
    ws[2048 + 4 * i]     = sg * 0.5 * (1.0 - s);   // A.x
    ws[2048 + 4 * i + 1] = sg * -0.5 * c;          // A.y
    ws[2048 + 4 * i + 2] = sg * 0.5 * (1.0 + s);   // B.x
    ws[2048 + 4 * i + 3] = sg * 0.5 * c;           // B.y
  }
}

// rows n_frames..n_rows-1 stay zero in the reference; d_out is poisoned, so write them.
__global__ void zero_tail(float* __restrict__ out) {
  int i = blockIdx.x * 256 + threadIdx.x;
  if (i < (MAG_SZ - FRAMES_FLOATS)) {   // 1539 per output
    out[FRAMES_FLOATS + i] = 0.0f;
    out[MAG_SZ + FRAMES_FLOATS + i] = 0.0f;
  }
}

#define CMUL(vr, vi, wx, wy) { double _t = (vr)*(wx) - (vi)*(wy); \
                               (vi) = (vr)*(wy) + (vi)*(wx); (vr) = _t; }

// In-place 8-point DFT, natural order in and out. y[k] = sum_n a[n] W8^{nk}.
__device__ __forceinline__ void dft8(double* ar, double* ai) {
  const double S = 0.70710678118654752440;  // sqrt(2)/2
  double s0r = ar[0] + ar[4], s0i = ai[0] + ai[4];
  double s1r = ar[0] - ar[4], s1i = ai[0] - ai[4];
  double s2r = ar[2] + ar[6], s2i = ai[2] + ai[6];
  double s3r = ar[2] - ar[6], s3i = ai[2] - ai[6];
  double t0r = ar[1] + ar[5], t0i = ai[1] + ai[5];
  double t1r = ar[1] - ar[5], t1i = ai[1] - ai[5];
  double t2r = ar[3] + ar[7], t2i = ai[3] + ai[7];
  double t3r = ar[3] - ar[7], t3i = ai[3] - ai[7];

  double e0r = s0r + s2r, e0i = s0i + s2i;
  double e2r = s0r - s2r, e2i = s0i - s2i;
  double e1r = s1r + s3i, e1i = s1i - s3r;   // s1 - i*s3
  double e3r = s1r - s3i, e3i = s1i + s3r;   // s1 + i*s3
  double o0r = t0r + t2r, o0i = t0i + t2i;
  double o2r = t0r - t2r, o2i = t0i - t2i;
  double o1r = t1r + t3i, o1i = t1i - t3r;
  double o3r = t1r - t3i, o3i = t1i + t3r;

  double u1r = S * (o1r + o1i), u1i = S * (o1i - o1r);   // W8^1 * o1
  double u2r = o2i,             u2i = -o2r;              // -i   * o2
  double u3r = S * (o3i - o3r), u3i = -S * (o3r + o3i);  // W8^3 * o3

  ar[0] = e0r + o0r; ai[0] = e0i + o0i;
  ar[4] = e0r - o0r; ai[4] = e0i - o0i;
  ar[1] = e1r + u1r; ai[1] = e1i + u1i;
  ar[5] = e1r - u1r; ai[5] = e1i - u1i;
  ar[2] = e2r + u2r; ai[2] = e2i + u2i;
  ar[6] = e2r - u2r; ai[6] = e2i - u2i;
  ar[3] = e3r + u3r; ai[3] = e3i + u3i;
  ar[7] = e3r - u3r; ai[7] = e3i - u3i;
}

// atan2 via min/max ratio + degree-11 minimax poly on [0,1].
// Max abs error ~1e-5 rad; branch-cut side decided by sign(y) exactly as
// libm (copysign), so +/-pi cuts at nulls are identical.
__device__ __forceinline__ float fast_atan2f(float y, float x) {
  const float PI   = 3.14159265358979f;
  const float PI_2 = 1.57079632679490f;
  float ax = fabsf(x), ay = fabsf(y);
  float mx = fmaxf(ax, ay), mn = fminf(ax, ay);
  float t = mn * __builtin_amdgcn_rcpf(mx);
  t = (mx == 0.0f) ? 0.0f : t;          // atan2(0,0) -> 0
  float zz = t * t;
  float a = fmaf(zz, -0.01172120f, 0.05265332f);
  a = fmaf(zz, a, -0.11643287f);
  a = fmaf(zz, a,  0.19354346f);
  a = fmaf(zz, a, -0.33262347f);
  a = fmaf(zz, a,  0.99997726f);
  a = a * t;                            // atan(mn/mx) in [0, pi/4]
  a = (ay > ax) ? (PI_2 - a) : a;
  a = (x < 0.0f) ? (PI - a) : a;
  return copysignf(a, y);
}

__global__ __launch_bounds__(64, 4) void stft_frame(const float* __restrict__ x,
                                                    const double* __restrict__ ws,
                                                    float* __restrict__ out) {
  __shared__ double2 zA[512];   // 8 KB
  __shared__ double2 zB[512];   // 8 KB  -> 16 KB/block (1 wave, 2 frames)

  const int l = threadIdx.x;    // 0..63 (one wave per block)
  const int g = l >> 3;         // high octal digit of lane
  const int q = l & 7;          // low octal digit of lane

  const int fa = blockIdx.x * 2;
  const int fb = fa + 1;
  const bool bvalid = (fb < N_FRAMES);

  // ---- shared input load: frames overlap by 768 samples ----
  // frame A needs x[baseA + 128m + 2l], m=0..7; frame B = same with m+2.
  float2 xv[10];
  const int baseA = fa * 256 - 768;
  if (baseA >= 0 && baseA + 1280 <= SIG_LEN) {
    // fast path: all but 4 of 32770 blocks
#pragma unroll
    for (int m = 0; m < 10; ++m)
      xv[m] = *(const float2*)(x + baseA + 128 * m + 2 * l);
  } else {
#pragma unroll
    for (int m = 0; m < 10; ++m) {
      int ix = baseA + 128 * m + 2 * l;
      float a0 = (ix >= 0 && ix < SIG_LEN) ? x[ix] : 0.0f;
      float a1 = (ix + 1 >= 0 && ix + 1 < SIG_LEN) ? x[ix + 1] : 0.0f;
      xv[m] = make_float2(a0, a1);
    }
  }

  // ---- window both frames (shared window regs) ----
  double aar[8], aai[8], bar[8], bai[8];
#pragma unroll
  for (int n2 = 0; n2 < 8; ++n2) {
    double2 wn = *(const double2*)(ws + 128 * n2 + 2 * l);
    aar[n2] = (double)xv[n2].x     * wn.x;
    aai[n2] = (double)xv[n2].y     * wn.y;
    bar[n2] = (double)xv[n2 + 2].x * wn.x;
    bai[n2] = (double)xv[n2 + 2].y * wn.y;
  }

  // ---- stage 1: DFT over n2 (reg axis) -> k0; twiddle W512^{l*k0} ----
  dft8(aar, aai);
  dft8(bar, bai);
  {
    const double2* tw1 = (const double2*)(ws + 1024) + l * 7;
#pragma unroll
    for (int r = 1; r < 8; ++r) {
      double2 w = tw1[r - 1];
      CMUL(aar[r], aai[r], w.x, w.y);
      CMUL(bar[r], bai[r], w.x, w.y);
    }
  }

  // ---- exchange A: idx_A(k0,n1,n0) = 64*k0 + 8*n1 + (n0^n1) ----
#pragma unroll
  for (int r = 0; r < 8; ++r) {
    int e = 64 * r + 8 * g + (q ^ g);
    zA[e] = make_double2(aar[r], aai[r]);
    zB[e] = make_double2(bar[r], bai[r]);
  }
  asm volatile("s_waitcnt lgkmcnt(0)" ::: "memory");
#pragma unroll
  for (int r = 0; r < 8; ++r) {
    int e = 64 * g + 8 * r + (q ^ r);
    double2 va = zA[e], vb = zB[e];
    aar[r] = va.x; aai[r] = va.y;
    bar[r] = vb.x; bai[r] = vb.y;
  }

  // ---- stage 2: DFT over n1 -> k1; twiddle W64^{n0*k1}, n0=q ----
  dft8(aar, aai);
  dft8(bar, bai);
  {
    const double2* tw2 = (const double2*)(ws + 1920) + q * 7;
#pragma unroll
    for (int r = 1; r < 8; ++r) {
      double2 w = tw2[r - 1];
      CMUL(aar[r], aai[r], w.x, w.y);
      CMUL(bar[r], bai[r], w.x, w.y);
    }
  }

  // ---- exchange B: idx_B(k0,k1,n0) = 64*k0 + 8*k1 + (n0^k1) ----
  // (DS ops are in-order per wave: writes cannot pass the prior reads)
#pragma unroll
  for (int r = 0; r < 8; ++r) {
    int e = 64 * g + 8 * r + (q ^ r);
    zA[e] = make_double2(aar[r], aai[r]);
    zB[e] = make_double2(bar[r], bai[r]);
  }
  asm volatile("s_waitcnt lgkmcnt(0)" ::: "memory");
#pragma unroll
  for (int r = 0; r < 8; ++r) {
    int e = 64 * g + 8 * q + (r ^ q);
    double2 va = zA[e], vb = zB[e];
    aar[r] = va.x; aai[r] = va.y;
    bar[r] = vb.x; bai[r] = vb.y;
  }

  // ---- stage 3: DFT over n0 -> k2; reg k2 = X[k], k = 64*k2 + 8*q + g ----
  dft8(aar, aai);
  dft8(bar, bai);

  // ---- partner store: only bins 256..511 (regs 4..7), swizzled ----
  // X[b], b = 64i+8q+g  ->  addr = 64(i-4) + 8q + (g^q)   (bijective)
#pragma unroll
  for (int r = 4; r < 8; ++r) {
    int e = 64 * (r - 4) + 8 * q + (g ^ q);
    zA[e] = make_double2(aar[r], aai[r]);
    zB[e] = make_double2(bar[r], bai[r]);
  }
  asm volatile("s_waitcnt lgkmcnt(0)" ::: "memory");

  // ---- epilogue: Zk from registers, Zm from partner store ----
  // Y_k      = Zk*A + conj(Zm)*B         (tables pre-scaled by (-1)^k)
  // Y_{512-k}= conj(conj(Zm)*A + Zk*B)
  const double* AB = ws + 2048;
  float* outmA = out + fa * HALF_N;
  float* outpA = out + MAG_SZ + fa * HALF_N;
  float* outmB = outmA + HALF_N;
  float* outpB = outpA + HALF_N;
#pragma unroll
  for (int i = 0; i < 4; ++i) {
    int k  = 64 * i + 8 * q + g;           // 0..255, bijective over (i,q,g)
    int km = 512 - k;                      // 257..512
    // partner addr: digits of b=km&511 with low3 := bg^bq (km=512 -> fixed below)
    int addr = ((km - 256) & ~7) | ((km ^ (km >> 3)) & 7);
    double2 ZmA = zA[addr], ZmB = zB[addr];
    if (i == 0 && l == 0) {                // k==0: Zm = Z[0] = Zk
      ZmA = make_double2(aar[0], aai[0]);
      ZmB = make_double2(bar[0], bai[0]);
    }
    const double* ab = AB + 4 * k;
    double Ax = ab[0], Ay = ab[1], Bx = ab[2], By = ab[3];

    double Yr  = aar[i] * Ax - aai[i] * Ay + ZmA.x * Bx + ZmA.y * By;
    double Yi  = aar[i] * Ay + aai[i] * Ax + ZmA.x * By - ZmA.y * Bx;
    double Y2r = ZmA.x * Ax + ZmA.y * Ay + aar[i] * Bx - aai[i] * By;
    double Y2i = -(ZmA.x * Ay - ZmA.y * Ax + aar[i] * By + aai[i] * Bx);

    double Wr  = bar[i] * Ax - bai[i] * Ay + ZmB.x * Bx + ZmB.y * By;
    double Wi  = bar[i] * Ay + bai[i] * Ax + ZmB.x * By - ZmB.y * Bx;
    double W2r = ZmB.x * Ax + ZmB.y * Ay + bar[i] * Bx - bai[i] * By;
    double W2i = -(ZmB.x * Ay - ZmB.y * Ax + bar[i] * By + bai[i] * Bx);

    if (i == 0 && l == 0) {                // bins 0 and 512: exactly real
      Yi = 0.0; Y2i = 0.0; Wi = 0.0; W2i = 0.0;
    }
    float yr  = (float)Yr,  yi  = (float)Yi;
    float y2r = (float)Y2r, y2i = (float)Y2i;
    outmA[k]  = __builtin_amdgcn_sqrtf(fmaf(yr, yr, yi * yi));
    outpA[k]  = fast_atan2f(yi, yr);
    outmA[km] = __builtin_amdgcn_sqrtf(fmaf(y2r, y2r, y2i * y2i));
    outpA[km] = fast_atan2f(y2i, y2r);
    if (bvalid) {
      float wr  = (float)Wr,  wi  = (float)Wi;
      float w2r = (float)W2r, w2i = (float)W2i;
      outmB[k]  = __builtin_amdgcn_sqrtf(fmaf(wr, wr, wi * wi));
      outpB[k]  = fast_atan2f(wi, wr);
      outmB[km] = __builtin_amdgcn_sqrtf(fmaf(w2r, w2r, w2i * w2i));
      outpB[km] = fast_atan2f(w2i, w2r);
    }
  }

  // ---- bin 256: A=0, B=1 exactly -> Y = conj(X[256]) = conj(reg 4 @ lane 0) ----
  if (l == 0) {
    float yr = (float)aar[4], yi = (float)(-aai[4]);
    outmA[256] = __builtin_amdgcn_sqrtf(fmaf(yr, yr, yi * yi));
    outpA[256] = fast_atan2f(yi, yr);      // (-1)^256 = +1
    if (bvalid) {
      float wr = (float)bar[4], wi = (float)(-bai[4]);
      outmB[256] = __builtin_amdgcn_sqrtf(fmaf(wr, wr, wi * wi));
      outpB[256] = fast_atan2f(wi, wr);
    }
  }
}

extern "C" void kernel_launch(void* const* d_in, const int* in_sizes, int n_in,
                              void* d_out, int out_size, void* d_ws, size_t ws_size,
                              hipStream_t stream) {
  const float* x = (const float*)d_in[0];
  float* out = (float*)d_out;
  double* ws = (double*)d_ws;

  hipLaunchKernelGGL(init_tables, dim3(4), dim3(256), 0, stream, ws);
  hipLaunchKernelGGL(zero_tail, dim3(7), dim3(256), 0, stream, out);
  hipLaunchKernelGGL(stft_frame, dim3((N_FRAMES + 1) / 2), dim3(64), 0, stream,
                     x, ws, out);
}